// Round 12
// baseline (44.649 us; speedup 1.0000x reference)
//
#include <hip/hip_runtime.h>
#include <hip/hip_cooperative_groups.h>

namespace cg = cooperative_groups;

#define NPTS 512
#define DIM 128
#define MARGIN 0.2f
#define ATILE 2
#define NBLK (NPTS / ATILE)     // 256 blocks = 1 per CU (exactly co-resident)
#define TROWS 256               // rows per LDS stage tile
#define NTILE (NPTS / TROWS)    // 2 tiles
#define NTHR 512

// R11's proven partial structure, single cooperative dispatch:
// partials -> grid.sync() -> block 0 reduces and writes out.
__global__ __launch_bounds__(NTHR) void triplet_coop_kernel(
    const float* __restrict__ z, const int* __restrict__ labels,
    float* __restrict__ psum, unsigned* __restrict__ pcnt,
    unsigned* __restrict__ pntrip, float* __restrict__ out)
{
    __shared__ float4 stage[TROWS * 32];                 // 128 KB
    __shared__ float part[4][TROWS][ATILE];              // 8 KB
    __shared__ float drow[ATILE][NPTS];                  // 4 KB
    __shared__ __align__(16) float pdm[ATILE][NPTS];     // 4 KB
    __shared__ int wcnt[ATILE][8];
    __shared__ float red_f[8];
    __shared__ unsigned red_c[8], red_n[8];

    const int t = threadIdx.x;
    const int b = blockIdx.x;
    const int a0 = b * ATILE;
    const int wid = t >> 6, lane = t & 63;
    const int q = t >> 7;               // k-quarter (uniform per wave)
    const int r = t & 127;              // base row; thread covers r and r+128

    const float4* zg = reinterpret_cast<const float4*>(z);

    // Anchor rows (own k-quarter) in registers; lane-uniform addr -> 1 txn each.
    float4 za[ATILE][8];
    #pragma unroll
    for (int i = 0; i < ATILE; ++i)
        #pragma unroll
        for (int kk = 0; kk < 8; ++kk)
            za[i][kk] = zg[(size_t)(a0 + i) * 32 + q * 8 + kk];

    // ---- distance phase: 2 staged tiles of 256 rows (R11-verbatim) ----
    for (int T = 0; T < NTILE; ++T) {
        #pragma unroll
        for (int p = 0; p < 16; ++p) {                   // coalesced stage
            int f = p * 512 + t;                         // 0..8191
            int row = f >> 5, chunk = f & 31;
            stage[row * 32 + (chunk ^ (row & 7))] =
                zg[(size_t)(T * TROWS + row) * 32 + chunk];
        }
        __syncthreads();                                 // stage ready; prev part reads done

        #pragma unroll
        for (int rr = 0; rr < 2; ++rr) {                 // rows r and r+128
            const int row = r + rr * 128;
            const int rx = row & 7;
            float acc0 = 0.f, acc1 = 0.f;
            #pragma unroll
            for (int kk = 0; kk < 8; ++kk) {
                float4 v = stage[row * 32 + ((q * 8 + kk) ^ rx)];
                float4 w0 = za[0][kk], w1 = za[1][kk];
                float d0 = w0.x - v.x, d1 = w0.y - v.y, d2 = w0.z - v.z, d3 = w0.w - v.w;
                acc0 += d0 * d0 + d1 * d1 + d2 * d2 + d3 * d3;
                float e0 = w1.x - v.x, e1 = w1.y - v.y, e2 = w1.z - v.z, e3 = w1.w - v.w;
                acc1 += e0 * e0 + e1 * e1 + e2 * e2 + e3 * e3;
            }
            part[q][row][0] = acc0;
            part[q][row][1] = acc1;
        }
        __syncthreads();                                 // part ready; stage reads done

        {                                                // all 512 threads do sqrt
            const int rr = t & 255, ii = t >> 8;
            float s = part[0][rr][ii] + part[1][rr][ii]
                    + part[2][rr][ii] + part[3][rr][ii];
            drow[ii][T * TROWS + rr] = sqrtf(s);
        }
        // next iteration's stage-sync orders part reads vs next part writes
    }
    __syncthreads();                                     // drow complete

    // ---- compact positives per anchor (R4-verbatim tail) ----
    const int lt = labels[t];
    int la[ATILE];
    #pragma unroll
    for (int i = 0; i < ATILE; ++i) la[i] = labels[a0 + i];

    bool pred[ATILE];
    unsigned long long m[ATILE];
    #pragma unroll
    for (int i = 0; i < ATILE; ++i) {
        pred[i] = (lt == la[i]) && (t != a0 + i);
        m[i] = __ballot(pred[i]);
        if (lane == 0) wcnt[i][wid] = (int)__popcll(m[i]);
    }
    __syncthreads();

    unsigned np[ATILE], npad[ATILE];
    #pragma unroll
    for (int i = 0; i < ATILE; ++i) {
        unsigned base = 0, n = 0;
        #pragma unroll
        for (int w = 0; w < 8; ++w) {
            unsigned c = (unsigned)wcnt[i][w];
            if (w < wid) base += c;
            n += c;
        }
        np[i] = n;
        npad[i] = (n + 3u) & ~3u;
        if (pred[i])
            pdm[i][base + __popcll(m[i] & ((1ull << lane) - 1ull))] = drow[i][t] + MARGIN;
        if ((unsigned)t >= n && (unsigned)t < npad[i])
            pdm[i][t] = -1e30f;                          // padding never fires relu
    }
    __syncthreads();

    // ---- accumulate: thread t = negative candidate t ----
    float sum = 0.f;
    unsigned cnt = 0;
    #pragma unroll
    for (int i = 0; i < ATILE; ++i) {
        if (lt != la[i]) {
            const float si = drow[i][t];
            const float4* p4 = reinterpret_cast<const float4*>(pdm[i]);
            const int n4 = (int)(npad[i] >> 2);
            for (int p = 0; p < n4; ++p) {
                float4 qv = p4[p];                       // LDS broadcast
                float v0 = qv.x - si, v1 = qv.y - si, v2 = qv.z - si, v3 = qv.w - si;
                if (v0 > 0.f) { sum += v0; ++cnt; }
                if (v1 > 0.f) { sum += v1; ++cnt; }
                if (v2 > 0.f) { sum += v2; ++cnt; }
                if (v3 > 0.f) { sum += v3; ++cnt; }
            }
        }
    }

    // ---- block reduction ----
    #pragma unroll
    for (int off = 32; off > 0; off >>= 1) {
        sum += __shfl_down(sum, off, 64);
        cnt += __shfl_down(cnt, off, 64);
    }
    if (lane == 0) { red_f[wid] = sum; red_c[wid] = cnt; }
    __syncthreads();
    if (t == 0) {
        float S = 0.f;
        unsigned C = 0;
        #pragma unroll
        for (int w = 0; w < 8; ++w) { S += red_f[w]; C += red_c[w]; }
        unsigned NT = 0;
        #pragma unroll
        for (int i = 0; i < ATILE; ++i) NT += np[i] * (unsigned)(NPTS - 1 - np[i]);
        psum[b] = S;
        pcnt[b] = C;
        pntrip[b] = NT;
    }

    // ---- grid-wide sync (proper, race-free), then block 0 finalizes ----
    cg::this_grid().sync();

    if (b == 0) {
        float s = 0.f;
        unsigned c = 0, nt = 0;
        if (t < NBLK) {
            s = psum[t]; c = pcnt[t]; nt = pntrip[t];
        }
        #pragma unroll
        for (int off = 32; off > 0; off >>= 1) {
            s  += __shfl_down(s,  off, 64);
            c  += __shfl_down(c,  off, 64);
            nt += __shfl_down(nt, off, 64);
        }
        if (lane == 0) { red_f[wid] = s; red_c[wid] = c; red_n[wid] = nt; }
        __syncthreads();
        if (t == 0) {
            double S = 0.0;
            unsigned C = 0, NT = 0;
            #pragma unroll
            for (int w = 0; w < 4; ++w) {   // entries 0..255 live in waves 0..3
                S += (double)red_f[w]; C += red_c[w]; NT += red_n[w];
            }
            out[0] = (float)(S / (double)NT);
            out[1] = (float)C;
        }
    }
}

extern "C" void kernel_launch(void* const* d_in, const int* in_sizes, int n_in,
                              void* d_out, int out_size, void* d_ws, size_t ws_size,
                              hipStream_t stream) {
    const float* z = (const float*)d_in[0];
    const int* labels = (const int*)d_in[1];
    float* out = (float*)d_out;

    float* psum = (float*)d_ws;
    unsigned* pcnt = (unsigned*)((char*)d_ws + NBLK * sizeof(float));
    unsigned* pntrip = pcnt + NBLK;

    void* args[] = { (void*)&z, (void*)&labels, (void*)&psum,
                     (void*)&pcnt, (void*)&pntrip, (void*)&out };
    hipLaunchCooperativeKernel((void*)triplet_coop_kernel,
                               dim3(NBLK), dim3(NTHR), args, 0, stream);
}

// Round 13
// 24.485 us; speedup vs baseline: 1.8235x; 1.8235x over previous
//
#include <hip/hip_runtime.h>

#define NPTS 512
#define DIM 128
#define MARGIN 0.2f
#define ATILE 2
#define NBLK (NPTS / ATILE)     // 256 blocks = 1 per CU
#define TROWS 256               // rows per LDS stage tile
#define NTILE (NPTS / TROWS)    // 2 tiles
#define NTHR 512

// R11's structure + ONE change: tile 1 is prefetched into registers before
// tile 0's compute (async-split staging), write-late after the part barrier.
__global__ __launch_bounds__(NTHR) void triplet_partial_kernel(
    const float* __restrict__ z, const int* __restrict__ labels,
    float* __restrict__ psum, unsigned* __restrict__ pcnt,
    unsigned* __restrict__ pntrip)
{
    __shared__ float4 stage[TROWS * 32];                 // 128 KB
    __shared__ float part[4][TROWS][ATILE];              // 8 KB
    __shared__ float drow[ATILE][NPTS];                  // 4 KB
    __shared__ __align__(16) float pdm[ATILE][NPTS];     // 4 KB
    __shared__ int wcnt[ATILE][8];
    __shared__ float red_f[8];
    __shared__ unsigned red_c[8];

    const int t = threadIdx.x;
    const int b = blockIdx.x;
    const int a0 = b * ATILE;
    const int wid = t >> 6, lane = t & 63;
    const int q = t >> 7;               // k-quarter (uniform per wave)
    const int r = t & 127;              // base row; thread covers r and r+128

    const float4* zg = reinterpret_cast<const float4*>(z);

    // Early tiny loads (latency hidden under stage 0).
    const int lt = labels[t];
    int la[ATILE];
    #pragma unroll
    for (int i = 0; i < ATILE; ++i) la[i] = labels[a0 + i];

    // Anchor rows (own k-quarter); lane-uniform addr -> 1 txn each.
    float4 za[ATILE][8];
    #pragma unroll
    for (int i = 0; i < ATILE; ++i)
        #pragma unroll
        for (int kk = 0; kk < 8; ++kk)
            za[i][kk] = zg[(size_t)(a0 + i) * 32 + q * 8 + kk];

    // ---- stage tile 0 (coalesced, both-sides XOR swizzle) ----
    #pragma unroll
    for (int p = 0; p < 16; ++p) {
        int f = p * 512 + t;                             // 0..8191
        int row = f >> 5, chunk = f & 31;
        stage[row * 32 + (chunk ^ (row & 7))] = zg[f];
    }
    __syncthreads();                                     // buf ready

    // ---- prefetch tile 1 into registers (latency hides under compute 0) ----
    float4 pf[16];
    #pragma unroll
    for (int p = 0; p < 16; ++p)
        pf[p] = zg[(size_t)(TROWS * 32) + p * 512 + t];

    // ---- compute tile 0 ----
    #pragma unroll
    for (int rr = 0; rr < 2; ++rr) {
        const int row = r + rr * 128;
        const int rx = row & 7;
        float acc0 = 0.f, acc1 = 0.f;
        #pragma unroll
        for (int kk = 0; kk < 8; ++kk) {
            float4 v = stage[row * 32 + ((q * 8 + kk) ^ rx)];
            float4 w0 = za[0][kk], w1 = za[1][kk];
            float d0 = w0.x - v.x, d1 = w0.y - v.y, d2 = w0.z - v.z, d3 = w0.w - v.w;
            acc0 += d0 * d0 + d1 * d1 + d2 * d2 + d3 * d3;
            float e0 = w1.x - v.x, e1 = w1.y - v.y, e2 = w1.z - v.z, e3 = w1.w - v.w;
            acc1 += e0 * e0 + e1 * e1 + e2 * e2 + e3 * e3;
        }
        part[q][row][0] = acc0;
        part[q][row][1] = acc1;
    }
    __syncthreads();                                     // part ready; stage reads done

    // sqrt tile 0 (all 512 threads) + write-late of prefetched tile 1
    {
        const int rr = t & 255, ii = t >> 8;
        float s = part[0][rr][ii] + part[1][rr][ii]
                + part[2][rr][ii] + part[3][rr][ii];
        drow[ii][rr] = sqrtf(s);
    }
    #pragma unroll
    for (int p = 0; p < 16; ++p) {
        int f = p * 512 + t;
        int row = f >> 5, chunk = f & 31;
        stage[row * 32 + (chunk ^ (row & 7))] = pf[p];
    }
    __syncthreads();                                     // buf ready; part reads done

    // ---- compute tile 1 ----
    #pragma unroll
    for (int rr = 0; rr < 2; ++rr) {
        const int row = r + rr * 128;
        const int rx = row & 7;
        float acc0 = 0.f, acc1 = 0.f;
        #pragma unroll
        for (int kk = 0; kk < 8; ++kk) {
            float4 v = stage[row * 32 + ((q * 8 + kk) ^ rx)];
            float4 w0 = za[0][kk], w1 = za[1][kk];
            float d0 = w0.x - v.x, d1 = w0.y - v.y, d2 = w0.z - v.z, d3 = w0.w - v.w;
            acc0 += d0 * d0 + d1 * d1 + d2 * d2 + d3 * d3;
            float e0 = w1.x - v.x, e1 = w1.y - v.y, e2 = w1.z - v.z, e3 = w1.w - v.w;
            acc1 += e0 * e0 + e1 * e1 + e2 * e2 + e3 * e3;
        }
        part[q][row][0] = acc0;
        part[q][row][1] = acc1;
    }
    __syncthreads();                                     // part ready

    {
        const int rr = t & 255, ii = t >> 8;
        float s = part[0][rr][ii] + part[1][rr][ii]
                + part[2][rr][ii] + part[3][rr][ii];
        drow[ii][TROWS + rr] = sqrtf(s);
    }
    __syncthreads();                                     // drow complete

    // ---- compact positives per anchor (R4-verbatim tail) ----
    bool pred[ATILE];
    unsigned long long m[ATILE];
    #pragma unroll
    for (int i = 0; i < ATILE; ++i) {
        pred[i] = (lt == la[i]) && (t != a0 + i);
        m[i] = __ballot(pred[i]);
        if (lane == 0) wcnt[i][wid] = (int)__popcll(m[i]);
    }
    __syncthreads();

    unsigned np[ATILE], npad[ATILE];
    #pragma unroll
    for (int i = 0; i < ATILE; ++i) {
        unsigned base = 0, n = 0;
        #pragma unroll
        for (int w = 0; w < 8; ++w) {
            unsigned c = (unsigned)wcnt[i][w];
            if (w < wid) base += c;
            n += c;
        }
        np[i] = n;
        npad[i] = (n + 3u) & ~3u;
        if (pred[i])
            pdm[i][base + __popcll(m[i] & ((1ull << lane) - 1ull))] = drow[i][t] + MARGIN;
        if ((unsigned)t >= n && (unsigned)t < npad[i])
            pdm[i][t] = -1e30f;                          // padding never fires relu
    }
    __syncthreads();

    // ---- accumulate: thread t = negative candidate t ----
    float sum = 0.f;
    unsigned cnt = 0;
    #pragma unroll
    for (int i = 0; i < ATILE; ++i) {
        if (lt != la[i]) {
            const float si = drow[i][t];
            const float4* p4 = reinterpret_cast<const float4*>(pdm[i]);
            const int n4 = (int)(npad[i] >> 2);
            for (int p = 0; p < n4; ++p) {
                float4 qv = p4[p];                       // LDS broadcast
                float v0 = qv.x - si, v1 = qv.y - si, v2 = qv.z - si, v3 = qv.w - si;
                if (v0 > 0.f) { sum += v0; ++cnt; }
                if (v1 > 0.f) { sum += v1; ++cnt; }
                if (v2 > 0.f) { sum += v2; ++cnt; }
                if (v3 > 0.f) { sum += v3; ++cnt; }
            }
        }
    }

    // ---- block reduction ----
    #pragma unroll
    for (int off = 32; off > 0; off >>= 1) {
        sum += __shfl_down(sum, off, 64);
        cnt += __shfl_down(cnt, off, 64);
    }
    if (lane == 0) { red_f[wid] = sum; red_c[wid] = cnt; }
    __syncthreads();
    if (t == 0) {
        float S = 0.f;
        unsigned C = 0;
        #pragma unroll
        for (int w = 0; w < 8; ++w) { S += red_f[w]; C += red_c[w]; }
        unsigned NT = 0;
        #pragma unroll
        for (int i = 0; i < ATILE; ++i) NT += np[i] * (unsigned)(NPTS - 1 - np[i]);
        psum[b] = S;
        pcnt[b] = C;
        pntrip[b] = NT;
    }
}

// Deterministic reduction of the 256 per-block partials (R4-verbatim).
__global__ __launch_bounds__(256) void triplet_final_kernel(
    const float* __restrict__ psum, const unsigned* __restrict__ pcnt,
    const unsigned* __restrict__ pntrip, float* __restrict__ out)
{
    __shared__ float rf[4];
    __shared__ unsigned rc[4], rn[4];

    const int t = threadIdx.x;
    float s = psum[t];
    unsigned c = pcnt[t];
    unsigned nt = pntrip[t];

    #pragma unroll
    for (int off = 32; off > 0; off >>= 1) {
        s  += __shfl_down(s,  off, 64);
        c  += __shfl_down(c,  off, 64);
        nt += __shfl_down(nt, off, 64);
    }
    const int wid = t >> 6, lane = t & 63;
    if (lane == 0) { rf[wid] = s; rc[wid] = c; rn[wid] = nt; }
    __syncthreads();
    if (t == 0) {
        double S = 0.0;
        unsigned C = 0, NT = 0;
        #pragma unroll
        for (int w = 0; w < 4; ++w) { S += (double)rf[w]; C += rc[w]; NT += rn[w]; }
        out[0] = (float)(S / (double)NT);
        out[1] = (float)C;
    }
}

extern "C" void kernel_launch(void* const* d_in, const int* in_sizes, int n_in,
                              void* d_out, int out_size, void* d_ws, size_t ws_size,
                              hipStream_t stream) {
    const float* z = (const float*)d_in[0];
    const int* labels = (const int*)d_in[1];
    float* out = (float*)d_out;

    float* psum = (float*)d_ws;
    unsigned* pcnt = (unsigned*)((char*)d_ws + NBLK * sizeof(float));
    unsigned* pntrip = pcnt + NBLK;

    triplet_partial_kernel<<<NBLK, NTHR, 0, stream>>>(z, labels, psum, pcnt, pntrip);
    triplet_final_kernel<<<1, NBLK, 0, stream>>>(psum, pcnt, pntrip, out);
}

// Round 14
// 14.899 us; speedup vs baseline: 2.9968x; 1.6434x over previous
//
#include <hip/hip_runtime.h>

#define NPTS 512
#define DIM 128
#define MARGIN 0.2f
#define ATILE 2
#define NBLK (NPTS / ATILE)     // 256 blocks = 1 per CU
#define TROWS 256               // rows per LDS stage tile
#define NTILE (NPTS / TROWS)    // 2 tiles
#define NTHR 512

// Champion structure (R11): reg-staged 128KB tile x2, part[] k-reduce,
// full-width sqrt, two-kernel finish. One redundant barrier removed.
__global__ __launch_bounds__(NTHR) void triplet_partial_kernel(
    const float* __restrict__ z, const int* __restrict__ labels,
    float* __restrict__ psum, unsigned* __restrict__ pcnt,
    unsigned* __restrict__ pntrip)
{
    __shared__ float4 stage[TROWS * 32];                 // 128 KB
    __shared__ float part[4][TROWS][ATILE];              // 8 KB
    __shared__ float drow[ATILE][NPTS];                  // 4 KB
    __shared__ __align__(16) float pdm[ATILE][NPTS];     // 4 KB
    __shared__ int wcnt[ATILE][8];
    __shared__ float red_f[8];
    __shared__ unsigned red_c[8];

    const int t = threadIdx.x;
    const int b = blockIdx.x;
    const int a0 = b * ATILE;
    const int wid = t >> 6, lane = t & 63;
    const int q = t >> 7;               // k-quarter (uniform per wave)
    const int r = t & 127;              // base row; thread covers r and r+128

    const float4* zg = reinterpret_cast<const float4*>(z);

    // Anchor rows (own k-quarter) in registers; lane-uniform addr -> 1 txn each.
    float4 za[ATILE][8];
    #pragma unroll
    for (int i = 0; i < ATILE; ++i)
        #pragma unroll
        for (int kk = 0; kk < 8; ++kk)
            za[i][kk] = zg[(size_t)(a0 + i) * 32 + q * 8 + kk];

    // ---- distance phase: 2 staged tiles of 256 rows ----
    for (int T = 0; T < NTILE; ++T) {
        #pragma unroll
        for (int p = 0; p < 16; ++p) {                   // coalesced stage
            int f = p * 512 + t;                         // 0..8191
            int row = f >> 5, chunk = f & 31;
            stage[row * 32 + (chunk ^ (row & 7))] =
                zg[(size_t)(T * TROWS + row) * 32 + chunk];
        }
        __syncthreads();                                 // stage ready; prev part reads done

        #pragma unroll
        for (int rr = 0; rr < 2; ++rr) {                 // rows r and r+128
            const int row = r + rr * 128;
            const int rx = row & 7;
            float acc0 = 0.f, acc1 = 0.f;
            #pragma unroll
            for (int kk = 0; kk < 8; ++kk) {
                float4 v = stage[row * 32 + ((q * 8 + kk) ^ rx)];
                float4 w0 = za[0][kk], w1 = za[1][kk];
                float d0 = w0.x - v.x, d1 = w0.y - v.y, d2 = w0.z - v.z, d3 = w0.w - v.w;
                acc0 += d0 * d0 + d1 * d1 + d2 * d2 + d3 * d3;
                float e0 = w1.x - v.x, e1 = w1.y - v.y, e2 = w1.z - v.z, e3 = w1.w - v.w;
                acc1 += e0 * e0 + e1 * e1 + e2 * e2 + e3 * e3;
            }
            part[q][row][0] = acc0;
            part[q][row][1] = acc1;
        }
        __syncthreads();                                 // part ready; stage reads done

        {                                                // all 512 threads do sqrt
            const int rr = t & 255, ii = t >> 8;
            float s = part[0][rr][ii] + part[1][rr][ii]
                    + part[2][rr][ii] + part[3][rr][ii];
            drow[ii][T * TROWS + rr] = sqrtf(s);
        }
        // next iteration's stage-barrier orders part reads vs next part writes
    }
    // NOTE: no barrier here. The ballot phase below touches no LDS; the wcnt
    // barrier orders all drow writes against the pdm-phase drow reads.

    // ---- compact positives per anchor ----
    const int lt = labels[t];
    int la[ATILE];
    #pragma unroll
    for (int i = 0; i < ATILE; ++i) la[i] = labels[a0 + i];

    bool pred[ATILE];
    unsigned long long m[ATILE];
    #pragma unroll
    for (int i = 0; i < ATILE; ++i) {
        pred[i] = (lt == la[i]) && (t != a0 + i);
        m[i] = __ballot(pred[i]);
        if (lane == 0) wcnt[i][wid] = (int)__popcll(m[i]);
    }
    __syncthreads();                                     // wcnt ready; drow complete

    unsigned np[ATILE], npad[ATILE];
    #pragma unroll
    for (int i = 0; i < ATILE; ++i) {
        unsigned base = 0, n = 0;
        #pragma unroll
        for (int w = 0; w < 8; ++w) {
            unsigned c = (unsigned)wcnt[i][w];
            if (w < wid) base += c;
            n += c;
        }
        np[i] = n;
        npad[i] = (n + 3u) & ~3u;
        if (pred[i])
            pdm[i][base + __popcll(m[i] & ((1ull << lane) - 1ull))] = drow[i][t] + MARGIN;
        if ((unsigned)t >= n && (unsigned)t < npad[i])
            pdm[i][t] = -1e30f;                          // padding never fires relu
    }
    __syncthreads();

    // ---- accumulate: thread t = negative candidate t ----
    float sum = 0.f;
    unsigned cnt = 0;
    #pragma unroll
    for (int i = 0; i < ATILE; ++i) {
        if (lt != la[i]) {
            const float si = drow[i][t];
            const float4* p4 = reinterpret_cast<const float4*>(pdm[i]);
            const int n4 = (int)(npad[i] >> 2);
            for (int p = 0; p < n4; ++p) {
                float4 qv = p4[p];                       // LDS broadcast
                float v0 = qv.x - si, v1 = qv.y - si, v2 = qv.z - si, v3 = qv.w - si;
                if (v0 > 0.f) { sum += v0; ++cnt; }
                if (v1 > 0.f) { sum += v1; ++cnt; }
                if (v2 > 0.f) { sum += v2; ++cnt; }
                if (v3 > 0.f) { sum += v3; ++cnt; }
            }
        }
    }

    // ---- block reduction ----
    #pragma unroll
    for (int off = 32; off > 0; off >>= 1) {
        sum += __shfl_down(sum, off, 64);
        cnt += __shfl_down(cnt, off, 64);
    }
    if (lane == 0) { red_f[wid] = sum; red_c[wid] = cnt; }
    __syncthreads();
    if (t == 0) {
        float S = 0.f;
        unsigned C = 0;
        #pragma unroll
        for (int w = 0; w < 8; ++w) { S += red_f[w]; C += red_c[w]; }
        unsigned NT = 0;
        #pragma unroll
        for (int i = 0; i < ATILE; ++i) NT += np[i] * (unsigned)(NPTS - 1 - np[i]);
        psum[b] = S;
        pcnt[b] = C;
        pntrip[b] = NT;
    }
}

// Deterministic reduction of the 256 per-block partials.
__global__ __launch_bounds__(256) void triplet_final_kernel(
    const float* __restrict__ psum, const unsigned* __restrict__ pcnt,
    const unsigned* __restrict__ pntrip, float* __restrict__ out)
{
    __shared__ float rf[4];
    __shared__ unsigned rc[4], rn[4];

    const int t = threadIdx.x;
    float s = psum[t];
    unsigned c = pcnt[t];
    unsigned nt = pntrip[t];

    #pragma unroll
    for (int off = 32; off > 0; off >>= 1) {
        s  += __shfl_down(s,  off, 64);
        c  += __shfl_down(c,  off, 64);
        nt += __shfl_down(nt, off, 64);
    }
    const int wid = t >> 6, lane = t & 63;
    if (lane == 0) { rf[wid] = s; rc[wid] = c; rn[wid] = nt; }
    __syncthreads();
    if (t == 0) {
        double S = 0.0;
        unsigned C = 0, NT = 0;
        #pragma unroll
        for (int w = 0; w < 4; ++w) { S += (double)rf[w]; C += rc[w]; NT += rn[w]; }
        out[0] = (float)(S / (double)NT);
        out[1] = (float)C;
    }
}

extern "C" void kernel_launch(void* const* d_in, const int* in_sizes, int n_in,
                              void* d_out, int out_size, void* d_ws, size_t ws_size,
                              hipStream_t stream) {
    const float* z = (const float*)d_in[0];
    const int* labels = (const int*)d_in[1];
    float* out = (float*)d_out;

    float* psum = (float*)d_ws;
    unsigned* pcnt = (unsigned*)((char*)d_ws + NBLK * sizeof(float));
    unsigned* pntrip = pcnt + NBLK;

    triplet_partial_kernel<<<NBLK, NTHR, 0, stream>>>(z, labels, psum, pcnt, pntrip);
    triplet_final_kernel<<<1, NBLK, 0, stream>>>(psum, pcnt, pntrip, out);
}